// Round 8
// baseline (270.855 us; speedup 1.0000x reference)
//
#include <hip/hip_runtime.h>
#include <hip/hip_cooperative_groups.h>

namespace cg = cooperative_groups;

#define ALPHA_LEAKY 0.2f
#define EPS_F 1e-10f

#define BSHIFT 7            // parent bucket = 128 qi (binning granularity)
#define NBMAX 1024          // max parent buckets (Nq <= 131072)
#define CHUNK 16384         // edges per prep_coop block (~21-edge runs per bucket)
#define SUBSH 6             // sort_agg sub-bucket = 64 qi
#define SUBRANGE 64
#define KBUF_CAP 1536       // sub-bucket LDS capacity (avg 1024, +16 sigma)

__device__ __forceinline__ float readlane_f(float v, int lane) {
  return __int_as_float(__builtin_amdgcn_readlane(__float_as_int(v), lane));
}

// RNE float -> bf16
__device__ __forceinline__ unsigned short f2bf(float x) {
  unsigned int u = __float_as_uint(x);
  return (unsigned short)((u + 0x7fffu + ((u >> 16) & 1u)) >> 16);
}

// ---------------------------------------------------------------------------
// prep_coop (cooperative): the whole edge-binning pipeline in one kernel.
//   phase 0: block 0 zeroes gcnt (replaces hipMemsetAsync)
//   phase 1: per-block LDS hist of register-cached qi (one coalesced read)
//   phase 2: block 0 scans gcnt -> gbase/gcursor
//   phase 3: reserve per-bucket runs (one global atomic per bucket per
//            block), write (qi,ki) pairs in ~168B contiguous runs
// qv stays in registers across grid.sync — eq is read exactly once.
// ---------------------------------------------------------------------------
__global__ __launch_bounds__(1024) void prep_coop(
    const int* __restrict__ eq, const int* __restrict__ ek,
    int* __restrict__ gcnt, int* __restrict__ gbase,
    int* __restrict__ gcursor, int2* __restrict__ pairs, int E, int NB) {
  cg::grid_group grid = cg::this_grid();
  __shared__ int lcnt[NBMAX];
  __shared__ int lbase[NBMAX];
  __shared__ int wso[16];
  const int t = threadIdx.x;

  // phase 0
  if (blockIdx.x == 0)
    for (int i = t; i < NBMAX; i += 1024) gcnt[i] = 0;
  for (int i = t; i < NBMAX; i += 1024) lcnt[i] = 0;
  grid.sync();

  // phase 1: hist
  const int cbase = blockIdx.x * CHUNK;
  int4 qv[4];
#pragma unroll
  for (int j = 0; j < 4; ++j) {
    const int e0 = cbase + (((j << 10) + t) << 2);
    if (e0 + 3 < E) {
      qv[j] = *(const int4*)(eq + e0);
    } else {
      int tq[4] = {-1, -1, -1, -1};
      for (int r = 0; r < 4; ++r)
        if (e0 + r < E) tq[r] = eq[e0 + r];
      qv[j] = make_int4(tq[0], tq[1], tq[2], tq[3]);
    }
    if (qv[j].x >= 0) atomicAdd(&lcnt[qv[j].x >> BSHIFT], 1);
    if (qv[j].y >= 0) atomicAdd(&lcnt[qv[j].y >> BSHIFT], 1);
    if (qv[j].z >= 0) atomicAdd(&lcnt[qv[j].z >> BSHIFT], 1);
    if (qv[j].w >= 0) atomicAdd(&lcnt[qv[j].w >> BSHIFT], 1);
  }
  __syncthreads();
  for (int i = t; i < NB; i += 1024)
    if (lcnt[i]) atomicAdd(&gcnt[i], lcnt[i]);
  grid.sync();

  // phase 2: block 0 exclusive scan of gcnt[0..NB)
  if (blockIdx.x == 0) {
    const int lane = t & 63, wv = t >> 6;
    const int v = (t < NB) ? gcnt[t] : 0;
    int x = v;
#pragma unroll
    for (int off = 1; off < 64; off <<= 1) {
      const int y = __shfl_up(x, off, 64);
      if (lane >= off) x += y;
    }
    if (lane == 63) wso[wv] = x;
    __syncthreads();
    int woff = 0;
    for (int w = 0; w < wv; ++w) woff += wso[w];
    const int excl = woff + x - v;
    if (t < NB) { gbase[t] = excl; gcursor[t] = excl; }
  }
  grid.sync();

  // phase 3: reserve runs (lcnt still holds this block's counts) and bin
  for (int i = t; i < NB; i += 1024) {
    lbase[i] = lcnt[i] ? atomicAdd(&gcursor[i], lcnt[i]) : 0;
    lcnt[i] = 0;
  }
  __syncthreads();
#pragma unroll
  for (int j = 0; j < 4; ++j) {
    const int e0 = cbase + (((j << 10) + t) << 2);
    int4 kv;
    if (e0 + 3 < E) {
      kv = *(const int4*)(ek + e0);
    } else {
      int tk[4] = {0, 0, 0, 0};
      for (int r = 0; r < 4; ++r)
        if (e0 + r < E) tk[r] = ek[e0 + r];
      kv = make_int4(tk[0], tk[1], tk[2], tk[3]);
    }
    const int qs[4] = {qv[j].x, qv[j].y, qv[j].z, qv[j].w};
    const int ks[4] = {kv.x, kv.y, kv.z, kv.w};
#pragma unroll
    for (int r = 0; r < 4; ++r) {
      if (qs[r] >= 0) {
        const int bb = qs[r] >> BSHIFT;
        pairs[lbase[bb] + atomicAdd(&lcnt[bb], 1)] = make_int2(qs[r], ks[r]);
      }
    }
  }
}

// ---------------------------------------------------------------------------
// proj_all: fold + q-side gemv + kv projection in one kernel.
//   phase A: load W into LDS; wave0 computes u_q[d] = sum_o wq[o]W[o][d]
//            and c_q = wq.bias into LDS.
//   phase B: grid-stride gemv sq[n] = qnodes[n,:].u_q + c_q (4 nodes/wave).
//   phase C: grid-stride kv projection: Kp16[n,:] = bf16(kv[n,:]@W.T + b)
//            packed, and sk[n] = P[n,:].wk (folded attention dot).
// ---------------------------------------------------------------------------
__global__ __launch_bounds__(256) void proj_all(
    const float* __restrict__ qnodes, const float* __restrict__ kvnodes,
    const float* __restrict__ W, const float* __restrict__ pb,
    const float* __restrict__ aw, unsigned int* __restrict__ Kp16,
    float* __restrict__ sq, float* __restrict__ sk,
    int Nq, int Nk, int nWaves) {
  __shared__ float Ws[64 * 65];
  __shared__ float us[64];
  __shared__ float cq_s;
  const int t = threadIdx.x;
  for (int i = t; i < 4096; i += 256) Ws[(i >> 6) * 65 + (i & 63)] = W[i];
  __syncthreads();

  const int lane = t & 63;
  const int waveId = blockIdx.x * 4 + (t >> 6);

  // phase A: u_q, c_q (wave 0)
  if (t < 64) {
    float s = 0.f;
    for (int o = 0; o < 64; ++o) s = fmaf(aw[o], Ws[o * 65 + t], s);
    us[t] = s;
    if (t == 0) {
      float c = 0.f;
      for (int o = 0; o < 64; ++o) c = fmaf(aw[o], pb[o], c);
      cq_s = c;
    }
  }
  __syncthreads();

  // phase B: sq over qnodes (4 nodes per wave-iter)
  {
    const int sub = lane & 15, ng = lane >> 4;
    const float4 uv = ((const float4*)us)[sub];
    const float c = cq_s;
    for (int base = waveId * 4; base < Nq; base += nWaves * 4) {
      const int n = base + ng;
      float s = 0.f;
      if (n < Nq) {
        const float4 x = *(const float4*)(qnodes + (size_t)n * 64 + sub * 4);
        s = x.x * uv.x + x.y * uv.y + x.z * uv.z + x.w * uv.w;
      }
#pragma unroll
      for (int off = 1; off <= 8; off <<= 1) s += __shfl_xor(s, off, 64);
      if (sub == 0 && n < Nq) sq[n] = s + c;
    }
  }

  // phase C: kv projection
  float wreg[64];
#pragma unroll
  for (int d = 0; d < 64; ++d) wreg[d] = Ws[lane * 65 + d];
  const float bl = pb[lane];
  const float avl = aw[64 + lane];

  for (int n = waveId; n < Nk; n += nWaves) {
    const float xv = kvnodes[(size_t)n * 64 + lane];
    float acc = bl;
#pragma unroll
    for (int d = 0; d < 64; ++d)
      acc = fmaf(readlane_f(xv, d), wreg[d], acc);
    const float nb = __shfl_xor(acc, 1, 64);
    if (!(lane & 1))
      Kp16[(size_t)n * 32 + (lane >> 1)] =
          ((unsigned int)f2bf(nb) << 16) | f2bf(acc);
    float ws = acc * avl;
#pragma unroll
    for (int off = 32; off > 0; off >>= 1) ws += __shfl_xor(ws, off, 64);
    if (lane == 0) sk[n] = ws;
  }
}

// ---------------------------------------------------------------------------
// sort_agg_kernel: one 256-thread block per 64-qi SUB-bucket (fine grain for
// occupancy/balance: ~6 blocks/CU, launch_bounds(256,8) -> low VGPR). Reads
// its parent 128-qi bucket's pairs twice (count then scatter; 2nd is L2-hot)
// instead of register-caching — keeps VGPRs low. LDS counting-sort of ki,
// then per-wave aggregation: 8 edge-groups x 8 dims, 2x unrolled (16 row
// gathers in flight), one coalesced normalized fp32 write per node.
// ---------------------------------------------------------------------------
__global__ __launch_bounds__(256, 8) void sort_agg_kernel(
    const int2* __restrict__ pairs, const int* __restrict__ gcnt,
    const int* __restrict__ gbase, const float* __restrict__ sq,
    const float* __restrict__ sk, const float* __restrict__ ab,
    const unsigned int* __restrict__ Kp16, float* __restrict__ out,
    int Nq) {
  __shared__ int cnt[SUBRANGE];
  __shared__ int cur[SUBRANGE];
  __shared__ int lstart[SUBRANGE + 1];
  __shared__ int kibuf[KBUF_CAP];

  const int t = threadIdx.x;
  const int b = blockIdx.x;         // sub-bucket id
  const int parent = b >> 1;
  const int qlo = b << SUBSH;
  const int n = gcnt[parent];
  const int base = gbase[parent];

  if (t < SUBRANGE) cnt[t] = 0;
  __syncthreads();

  // pass 1: count this sub-bucket's edges
  for (int i = t; i < n; i += 256) {
    const unsigned int local = (unsigned int)(pairs[base + i].x - qlo);
    if (local < SUBRANGE) atomicAdd(&cnt[local], 1);
  }
  __syncthreads();

  // wave 0: exclusive scan of cnt[0..63]
  if (t < SUBRANGE) {
    const int v = cnt[t];
    int x = v;
#pragma unroll
    for (int off = 1; off < 64; off <<= 1) {
      const int y = __shfl_up(x, off, 64);
      if (t >= off) x += y;
    }
    const int excl = x - v;
    lstart[t] = excl;
    cur[t] = excl;
    if (t == SUBRANGE - 1) lstart[SUBRANGE] = excl + v;
  }
  __syncthreads();

  // pass 2: scatter ki into kibuf (sorted by local qi)
  for (int i = t; i < n; i += 256) {
    const int2 p = pairs[base + i];
    const unsigned int local = (unsigned int)(p.x - qlo);
    if (local < SUBRANGE) {
      const int pos = atomicAdd(&cur[local], 1);
      if (pos < KBUF_CAP) kibuf[pos] = p.y;
    }
  }
  __syncthreads();

  // aggregation: wave wv -> local nodes wv, wv+4, ...
  const int lane = t & 63, wv = t >> 6;
  const int g = lane >> 3, sub = lane & 7;
  const float abv = ab[0];
  for (int l = wv; l < SUBRANGE; l += 4) {
    const int node = qlo + l;
    if (node >= Nq) break;
    const int s = lstart[l];
    const int e = lstart[l + 1];
    const float sqn = sq[node] + abv;

    float acc[8] = {0.f, 0.f, 0.f, 0.f, 0.f, 0.f, 0.f, 0.f};
    float wsum = 0.f;
    for (int j = s; j < e; j += 16) {
      const int i1 = j + g;
      const int i2 = j + 8 + g;
      int k1 = 0, k2 = 0;
      float w1 = 0.f, w2 = 0.f;
      if (i1 < e) {
        k1 = kibuf[i1];
        float x = sqn + sk[k1];
        x = x > 0.f ? x : ALPHA_LEAKY * x;
        w1 = __expf(x);
      }
      if (i2 < e) {
        k2 = kibuf[i2];
        float x = sqn + sk[k2];
        x = x > 0.f ? x : ALPHA_LEAKY * x;
        w2 = __expf(x);
      }
      const uint4 u1 = *(const uint4*)(Kp16 + (size_t)k1 * 32 + sub * 4);
      const uint4 u2 = *(const uint4*)(Kp16 + (size_t)k2 * 32 + sub * 4);
      acc[0] = fmaf(w1, __uint_as_float(u1.x << 16), acc[0]);
      acc[1] = fmaf(w1, __uint_as_float(u1.x & 0xffff0000u), acc[1]);
      acc[2] = fmaf(w1, __uint_as_float(u1.y << 16), acc[2]);
      acc[3] = fmaf(w1, __uint_as_float(u1.y & 0xffff0000u), acc[3]);
      acc[4] = fmaf(w1, __uint_as_float(u1.z << 16), acc[4]);
      acc[5] = fmaf(w1, __uint_as_float(u1.z & 0xffff0000u), acc[5]);
      acc[6] = fmaf(w1, __uint_as_float(u1.w << 16), acc[6]);
      acc[7] = fmaf(w1, __uint_as_float(u1.w & 0xffff0000u), acc[7]);
      wsum += w1;
      acc[0] = fmaf(w2, __uint_as_float(u2.x << 16), acc[0]);
      acc[1] = fmaf(w2, __uint_as_float(u2.x & 0xffff0000u), acc[1]);
      acc[2] = fmaf(w2, __uint_as_float(u2.y << 16), acc[2]);
      acc[3] = fmaf(w2, __uint_as_float(u2.y & 0xffff0000u), acc[3]);
      acc[4] = fmaf(w2, __uint_as_float(u2.z << 16), acc[4]);
      acc[5] = fmaf(w2, __uint_as_float(u2.z & 0xffff0000u), acc[5]);
      acc[6] = fmaf(w2, __uint_as_float(u2.w << 16), acc[6]);
      acc[7] = fmaf(w2, __uint_as_float(u2.w & 0xffff0000u), acc[7]);
      wsum += w2;
    }
#pragma unroll
    for (int off = 8; off <= 32; off <<= 1) {
#pragma unroll
      for (int i = 0; i < 8; ++i) acc[i] += __shfl_xor(acc[i], off, 64);
      wsum += __shfl_xor(wsum, off, 64);
    }
    if (g == 0) {
      const float inv = 1.0f / (wsum + EPS_F);
      float4 r0 = {acc[0] * inv, acc[1] * inv, acc[2] * inv, acc[3] * inv};
      float4 r1 = {acc[4] * inv, acc[5] * inv, acc[6] * inv, acc[7] * inv};
      float* o = out + (size_t)node * 64 + sub * 8;
      *(float4*)o = r0;
      *(float4*)(o + 4) = r1;
    }
  }
}

extern "C" void kernel_launch(void* const* d_in, const int* in_sizes, int n_in,
                              void* d_out, int out_size, void* d_ws, size_t ws_size,
                              hipStream_t stream) {
  const float* qnodes = (const float*)d_in[0];   // (Nq, 64) f32
  const float* kvnodes = (const float*)d_in[1];  // (Nk, 64) f32
  const int* ei = (const int*)d_in[2];           // (2, E) int32
  const float* W = (const float*)d_in[3];        // (64, 64)
  const float* pb = (const float*)d_in[4];       // (64,)
  const float* aw = (const float*)d_in[5];       // (1, 128): [wq | wk]
  const float* ab = (const float*)d_in[6];       // (1,)

  int Nq = in_sizes[0] / 64;
  int Nk = in_sizes[1] / 64;
  int E = in_sizes[2] / 2;
  int NB = (Nq + (1 << BSHIFT) - 1) >> BSHIFT;   // 782 at Nq=100000

  const int* eq = ei;
  const int* ek = ei + E;

  // --- workspace layout ---
  char* ws = (char*)d_ws;
  int2* pairs = (int2*)ws;                              // E int2
  unsigned int* Kp16 = (unsigned int*)(pairs + E);      // Nk*32 words
  float* sq = (float*)(Kp16 + (size_t)Nk * 32);         // Nq
  float* sk = sq + Nq;                                  // Nk
  int* gcnt = (int*)(sk + Nk);                          // NBMAX
  int* gbase = gcnt + NBMAX;                            // NBMAX
  int* gcursor = gbase + NBMAX;                         // NBMAX

  // --- edge binning: one cooperative kernel (zeroes gcnt itself) ---
  const int nChunks = (E + CHUNK - 1) / CHUNK;          // 98 at E=1.6M
  {
    void* args[] = {(void*)&eq, (void*)&ek, (void*)&gcnt, (void*)&gbase,
                    (void*)&gcursor, (void*)&pairs, (void*)&E, (void*)&NB};
    hipLaunchCooperativeKernel((const void*)prep_coop, dim3(nChunks),
                               dim3(1024), args, 0, stream);
  }

  // --- projections (fold + gemv + kv-proj fused) ---
  const int projBlocks = 1536;
  proj_all<<<projBlocks, 256, 0, stream>>>(qnodes, kvnodes, W, pb, aw, Kp16,
                                           sq, sk, Nq, Nk, projBlocks * 4);

  // --- fused sub-bucket sort + aggregation ---
  const int NBsub = (Nq + SUBRANGE - 1) >> SUBSH;       // 1563
  sort_agg_kernel<<<NBsub, 256, 0, stream>>>(pairs, gcnt, gbase, sq, sk, ab,
                                             Kp16, (float*)d_out, Nq);
}

// Round 9
// 213.536 us; speedup vs baseline: 1.2684x; 1.2684x over previous
//
#include <hip/hip_runtime.h>

#define ALPHA_LEAKY 0.2f
#define EPS_F 1e-10f

#define BSHIFT 7            // bucket = 128 qi
#define BRANGE 128
#define NBMAX 1024          // max buckets (Nq <= 131072)
#define CHUNK 16384         // edges per bin_kernel block
#define KBUF_CAP 3072       // bucket LDS capacity (avg 2048, +22 sigma)
#define HIST_BLOCKS 512

__device__ __forceinline__ float readlane_f(float v, int lane) {
  return __int_as_float(__builtin_amdgcn_readlane(__float_as_int(v), lane));
}

// RNE float -> bf16
__device__ __forceinline__ unsigned short f2bf(float x) {
  unsigned int u = __float_as_uint(x);
  return (unsigned short)((u + 0x7fffu + ((u >> 16) & 1u)) >> 16);
}

// ---------------------------------------------------------------------------
// hist_proj_kernel: two independent jobs in one launch (blockIdx split).
//  blocks [0, HIST_BLOCKS): LDS histogram of qi>>BSHIFT -> gcnt
//  blocks [HIST_BLOCKS, +projBlocks): fold + q-gemv + kv projection
// ---------------------------------------------------------------------------
__global__ __launch_bounds__(256) void hist_proj_kernel(
    const int* __restrict__ eq, int* __restrict__ gcnt, int E, int NB,
    const float* __restrict__ qnodes, const float* __restrict__ kvnodes,
    const float* __restrict__ W, const float* __restrict__ pb,
    const float* __restrict__ aw, unsigned int* __restrict__ Kp16,
    float* __restrict__ sq, float* __restrict__ sk,
    int Nq, int Nk, int projBlocks) {
  const int t = threadIdx.x;
  if (blockIdx.x < HIST_BLOCKS) {
    // ---- histogram ----
    __shared__ int lcnt[NBMAX];
    for (int i = t; i < NBMAX; i += 256) lcnt[i] = 0;
    __syncthreads();
    const int n4 = E >> 2;
    for (int i = blockIdx.x * 256 + t; i < n4; i += HIST_BLOCKS * 256) {
      const int4 q = ((const int4*)eq)[i];
      atomicAdd(&lcnt[q.x >> BSHIFT], 1);
      atomicAdd(&lcnt[q.y >> BSHIFT], 1);
      atomicAdd(&lcnt[q.z >> BSHIFT], 1);
      atomicAdd(&lcnt[q.w >> BSHIFT], 1);
    }
    if (blockIdx.x == 0 && t < (E & 3))
      atomicAdd(&lcnt[eq[(n4 << 2) + t] >> BSHIFT], 1);
    __syncthreads();
    for (int i = t; i < NB; i += 256)
      if (lcnt[i]) atomicAdd(&gcnt[i], lcnt[i]);
    return;
  }

  // ---- projections ----
  __shared__ float Ws[64 * 65];
  __shared__ float us[64];
  __shared__ float cq_s;
  const int bid = blockIdx.x - HIST_BLOCKS;
  for (int i = t; i < 4096; i += 256) Ws[(i >> 6) * 65 + (i & 63)] = W[i];
  __syncthreads();

  const int lane = t & 63;
  const int waveId = bid * 4 + (t >> 6);
  const int nWaves = projBlocks * 4;

  // fold: u_q, c_q (wave 0)
  if (t < 64) {
    float s = 0.f;
    for (int o = 0; o < 64; ++o) s = fmaf(aw[o], Ws[o * 65 + t], s);
    us[t] = s;
    if (t == 0) {
      float c = 0.f;
      for (int o = 0; o < 64; ++o) c = fmaf(aw[o], pb[o], c);
      cq_s = c;
    }
  }
  __syncthreads();

  // q-side gemv: sq[n] = qnodes[n,:].u_q + c_q (4 nodes per wave-iter)
  {
    const int sub = lane & 15, ng = lane >> 4;
    const float4 uv = ((const float4*)us)[sub];
    const float c = cq_s;
    for (int base = waveId * 4; base < Nq; base += nWaves * 4) {
      const int n = base + ng;
      float s = 0.f;
      if (n < Nq) {
        const float4 x = *(const float4*)(qnodes + (size_t)n * 64 + sub * 4);
        s = x.x * uv.x + x.y * uv.y + x.z * uv.z + x.w * uv.w;
      }
#pragma unroll
      for (int off = 1; off <= 8; off <<= 1) s += __shfl_xor(s, off, 64);
      if (sub == 0 && n < Nq) sq[n] = s + c;
    }
  }

  // kv projection: Kp16 bf16-packed + folded sk dot
  float wreg[64];
#pragma unroll
  for (int d = 0; d < 64; ++d) wreg[d] = Ws[lane * 65 + d];
  const float bl = pb[lane];
  const float avl = aw[64 + lane];

  for (int n = waveId; n < Nk; n += nWaves) {
    const float xv = kvnodes[(size_t)n * 64 + lane];
    float acc = bl;
#pragma unroll
    for (int d = 0; d < 64; ++d)
      acc = fmaf(readlane_f(xv, d), wreg[d], acc);
    const float nb = __shfl_xor(acc, 1, 64);
    if (!(lane & 1))
      Kp16[(size_t)n * 32 + (lane >> 1)] =
          ((unsigned int)f2bf(nb) << 16) | f2bf(acc);
    float ws = acc * avl;
#pragma unroll
    for (int off = 32; off > 0; off >>= 1) ws += __shfl_xor(ws, off, 64);
    if (lane == 0) sk[n] = ws;
  }
}

// ---------------------------------------------------------------------------
// bucket_scan: exclusive scan of gcnt[0..NB) -> gbase, gcursor. NB <= 1024.
// ---------------------------------------------------------------------------
__global__ __launch_bounds__(1024) void bucket_scan(
    const int* __restrict__ gcnt, int* __restrict__ gbase,
    int* __restrict__ gcursor, int NB) {
  __shared__ int wso[16];
  const int t = threadIdx.x, lane = t & 63, wv = t >> 6;
  const int v = (t < NB) ? gcnt[t] : 0;
  int x = v;
#pragma unroll
  for (int off = 1; off < 64; off <<= 1) {
    const int y = __shfl_up(x, off, 64);
    if (lane >= off) x += y;
  }
  if (lane == 63) wso[wv] = x;
  __syncthreads();
  int woff = 0;
  for (int w = 0; w < wv; ++w) woff += wso[w];
  const int excl = woff + x - v;
  if (t < NB) { gbase[t] = excl; gcursor[t] = excl; }
}

// ---------------------------------------------------------------------------
// bin_kernel: 1024 threads, 16384 edges/block: coalesced int4 reads into
// registers, LDS per-bucket count, ONE reservation atomic per bucket per
// block, (qi,ki) pairs written in ~168B contiguous runs.
// ---------------------------------------------------------------------------
__global__ __launch_bounds__(1024) void bin_kernel(
    const int* __restrict__ eq, const int* __restrict__ ek,
    int* __restrict__ gcursor, int2* __restrict__ pairs, int E, int NB) {
  __shared__ int lcnt[NBMAX];
  __shared__ int lbase[NBMAX];
  const int t = threadIdx.x;
  for (int i = t; i < NBMAX; i += 1024) lcnt[i] = 0;
  __syncthreads();

  const int cbase = blockIdx.x * CHUNK;
  int4 qv[4], kv[4];
#pragma unroll
  for (int j = 0; j < 4; ++j) {
    const int e0 = cbase + (((j << 10) + t) << 2);
    if (e0 + 3 < E) {
      qv[j] = *(const int4*)(eq + e0);
      kv[j] = *(const int4*)(ek + e0);
    } else {
      int tq[4] = {-1, -1, -1, -1}, tk[4] = {0, 0, 0, 0};
      for (int r = 0; r < 4; ++r)
        if (e0 + r < E) { tq[r] = eq[e0 + r]; tk[r] = ek[e0 + r]; }
      qv[j] = make_int4(tq[0], tq[1], tq[2], tq[3]);
      kv[j] = make_int4(tk[0], tk[1], tk[2], tk[3]);
    }
    if (qv[j].x >= 0) atomicAdd(&lcnt[qv[j].x >> BSHIFT], 1);
    if (qv[j].y >= 0) atomicAdd(&lcnt[qv[j].y >> BSHIFT], 1);
    if (qv[j].z >= 0) atomicAdd(&lcnt[qv[j].z >> BSHIFT], 1);
    if (qv[j].w >= 0) atomicAdd(&lcnt[qv[j].w >> BSHIFT], 1);
  }
  __syncthreads();
  for (int i = t; i < NB; i += 1024) {
    lbase[i] = lcnt[i] ? atomicAdd(&gcursor[i], lcnt[i]) : 0;
    lcnt[i] = 0;
  }
  __syncthreads();
#pragma unroll
  for (int j = 0; j < 4; ++j) {
    const int qs[4] = {qv[j].x, qv[j].y, qv[j].z, qv[j].w};
    const int ks[4] = {kv[j].x, kv[j].y, kv[j].z, kv[j].w};
#pragma unroll
    for (int r = 0; r < 4; ++r) {
      if (qs[r] >= 0) {
        const int b = qs[r] >> BSHIFT;
        pairs[lbase[b] + atomicAdd(&lcnt[b], 1)] = make_int2(qs[r], ks[r]);
      }
    }
  }
}

// ---------------------------------------------------------------------------
// sort_agg_kernel: one 512-thr block per 128-qi bucket (782 blocks ~3/CU).
// Phase A: register-cache the bucket's pairs, LDS counting-sort ki -> kibuf.
// Phase B (TRANSPOSED): lane = (node-sub ng 0..7, dim-group dg 0..7); each
// lane owns 8 dims of one node and walks that node's full edge list (2x
// unrolled). NO cross-lane reduction, no edge-slot padding: wsum is computed
// redundantly by the node's 8 lanes; each lane stores its own 32B directly
// (256B contiguous per node across its 8 lanes).
// ---------------------------------------------------------------------------
__global__ __launch_bounds__(512, 6) void sort_agg_kernel(
    const int2* __restrict__ pairs, const int* __restrict__ gcnt,
    const int* __restrict__ gbase, const float* __restrict__ sq,
    const float* __restrict__ sk, const float* __restrict__ ab,
    const unsigned int* __restrict__ Kp16, float* __restrict__ out,
    int Nq) {
  __shared__ int lcnt[BRANGE];
  __shared__ int lcur[BRANGE];
  __shared__ int lstart[BRANGE + 1];
  __shared__ int kibuf[KBUF_CAP];
  __shared__ int wso2[2];

  const int t = threadIdx.x;
  const int b = blockIdx.x;
  const int qlo = b << BSHIFT;
  int n = gcnt[b];
  if (n > KBUF_CAP) n = KBUF_CAP;  // statistically never; OOB guard
  const int base = gbase[b];

  if (t < BRANGE) lcnt[t] = 0;
  __syncthreads();

  // cache this thread's pairs (<= 6 at KBUF_CAP 3072)
  int2 pv[6];
  int np = 0;
#pragma unroll
  for (int r = 0; r < 6; ++r) {
    const int i = t + (r << 9);
    if (i < n) { pv[r] = pairs[base + i]; ++np; }
  }
#pragma unroll
  for (int r = 0; r < 6; ++r)
    if (r < np) atomicAdd(&lcnt[pv[r].x - qlo], 1);
  __syncthreads();

  // exclusive scan of lcnt[0..127] (first 2 waves)
  const int lane = t & 63, wv = t >> 6;
  int v = 0, x = 0;
  if (t < BRANGE) {
    v = lcnt[t];
    x = v;
#pragma unroll
    for (int off = 1; off < 64; off <<= 1) {
      const int y = __shfl_up(x, off, 64);
      if (lane >= off) x += y;
    }
    if (lane == 63) wso2[wv] = x;
  }
  __syncthreads();
  if (t < BRANGE) {
    const int excl = ((wv == 1) ? wso2[0] : 0) + x - v;
    lstart[t] = excl;
    lcur[t] = excl;
    if (t == BRANGE - 1) lstart[BRANGE] = excl + v;
  }
  __syncthreads();

  // scatter ki into kibuf (sorted by local qi)
#pragma unroll
  for (int r = 0; r < 6; ++r)
    if (r < np) kibuf[atomicAdd(&lcur[pv[r].x - qlo], 1)] = pv[r].y;
  __syncthreads();

  // Phase B: transposed aggregation. 8 waves x 8 nodes = 64 nodes per pass.
  const int ng = lane >> 3, dg = lane & 7;
  const float abv = ab[0];
#pragma unroll
  for (int pass = 0; pass < 2; ++pass) {
    const int l = (pass << 6) + (wv << 3) + ng;
    const int node = qlo + l;
    const bool act = node < Nq;
    const int s = act ? lstart[l] : 0;
    const int e = act ? lstart[l + 1] : 0;
    const float sqn = act ? sq[node] + abv : 0.f;

    float acc[8] = {0.f, 0.f, 0.f, 0.f, 0.f, 0.f, 0.f, 0.f};
    float wsum = 0.f;
    int j = s;
    for (; j + 1 < e; j += 2) {
      const int k1 = kibuf[j];
      const int k2 = kibuf[j + 1];
      float x1 = sqn + sk[k1];
      float x2 = sqn + sk[k2];
      x1 = x1 > 0.f ? x1 : ALPHA_LEAKY * x1;
      x2 = x2 > 0.f ? x2 : ALPHA_LEAKY * x2;
      const float w1 = __expf(x1);
      const float w2 = __expf(x2);
      const uint4 u1 = *(const uint4*)(Kp16 + (size_t)k1 * 32 + (dg << 2));
      const uint4 u2 = *(const uint4*)(Kp16 + (size_t)k2 * 32 + (dg << 2));
      acc[0] = fmaf(w1, __uint_as_float(u1.x << 16), acc[0]);
      acc[1] = fmaf(w1, __uint_as_float(u1.x & 0xffff0000u), acc[1]);
      acc[2] = fmaf(w1, __uint_as_float(u1.y << 16), acc[2]);
      acc[3] = fmaf(w1, __uint_as_float(u1.y & 0xffff0000u), acc[3]);
      acc[4] = fmaf(w1, __uint_as_float(u1.z << 16), acc[4]);
      acc[5] = fmaf(w1, __uint_as_float(u1.z & 0xffff0000u), acc[5]);
      acc[6] = fmaf(w1, __uint_as_float(u1.w << 16), acc[6]);
      acc[7] = fmaf(w1, __uint_as_float(u1.w & 0xffff0000u), acc[7]);
      acc[0] = fmaf(w2, __uint_as_float(u2.x << 16), acc[0]);
      acc[1] = fmaf(w2, __uint_as_float(u2.x & 0xffff0000u), acc[1]);
      acc[2] = fmaf(w2, __uint_as_float(u2.y << 16), acc[2]);
      acc[3] = fmaf(w2, __uint_as_float(u2.y & 0xffff0000u), acc[3]);
      acc[4] = fmaf(w2, __uint_as_float(u2.z << 16), acc[4]);
      acc[5] = fmaf(w2, __uint_as_float(u2.z & 0xffff0000u), acc[5]);
      acc[6] = fmaf(w2, __uint_as_float(u2.w << 16), acc[6]);
      acc[7] = fmaf(w2, __uint_as_float(u2.w & 0xffff0000u), acc[7]);
      wsum += w1 + w2;
    }
    if (j < e) {
      const int k1 = kibuf[j];
      float x1 = sqn + sk[k1];
      x1 = x1 > 0.f ? x1 : ALPHA_LEAKY * x1;
      const float w1 = __expf(x1);
      const uint4 u1 = *(const uint4*)(Kp16 + (size_t)k1 * 32 + (dg << 2));
      acc[0] = fmaf(w1, __uint_as_float(u1.x << 16), acc[0]);
      acc[1] = fmaf(w1, __uint_as_float(u1.x & 0xffff0000u), acc[1]);
      acc[2] = fmaf(w1, __uint_as_float(u1.y << 16), acc[2]);
      acc[3] = fmaf(w1, __uint_as_float(u1.y & 0xffff0000u), acc[3]);
      acc[4] = fmaf(w1, __uint_as_float(u1.z << 16), acc[4]);
      acc[5] = fmaf(w1, __uint_as_float(u1.z & 0xffff0000u), acc[5]);
      acc[6] = fmaf(w1, __uint_as_float(u1.w << 16), acc[6]);
      acc[7] = fmaf(w1, __uint_as_float(u1.w & 0xffff0000u), acc[7]);
      wsum += w1;
    }
    if (act) {
      const float inv = 1.0f / (wsum + EPS_F);
      float4 r0 = {acc[0] * inv, acc[1] * inv, acc[2] * inv, acc[3] * inv};
      float4 r1 = {acc[4] * inv, acc[5] * inv, acc[6] * inv, acc[7] * inv};
      float* o = out + (size_t)node * 64 + (dg << 3);
      *(float4*)o = r0;
      *(float4*)(o + 4) = r1;
    }
  }
}

extern "C" void kernel_launch(void* const* d_in, const int* in_sizes, int n_in,
                              void* d_out, int out_size, void* d_ws, size_t ws_size,
                              hipStream_t stream) {
  const float* qnodes = (const float*)d_in[0];   // (Nq, 64) f32
  const float* kvnodes = (const float*)d_in[1];  // (Nk, 64) f32
  const int* ei = (const int*)d_in[2];           // (2, E) int32
  const float* W = (const float*)d_in[3];        // (64, 64)
  const float* pb = (const float*)d_in[4];       // (64,)
  const float* aw = (const float*)d_in[5];       // (1, 128): [wq | wk]
  const float* ab = (const float*)d_in[6];       // (1,)

  const int Nq = in_sizes[0] / 64;
  const int Nk = in_sizes[1] / 64;
  const int E = in_sizes[2] / 2;
  const int NB = (Nq + BRANGE - 1) >> BSHIFT;    // 782 at Nq=100000

  const int* eq = ei;
  const int* ek = ei + E;

  // --- workspace layout ---
  char* ws = (char*)d_ws;
  int2* pairs = (int2*)ws;                              // E int2
  unsigned int* Kp16 = (unsigned int*)(pairs + E);      // Nk*32 words
  float* sq = (float*)(Kp16 + (size_t)Nk * 32);         // Nq
  float* sk = sq + Nq;                                  // Nk
  int* gcnt = (int*)(sk + Nk);                          // NBMAX
  int* gbase = gcnt + NBMAX;                            // NBMAX
  int* gcursor = gbase + NBMAX;                         // NBMAX

  hipMemsetAsync(gcnt, 0, NBMAX * sizeof(int), stream);

  // --- hist + projections (independent; fused into one launch) ---
  const int projBlocks = 1536;
  hist_proj_kernel<<<HIST_BLOCKS + projBlocks, 256, 0, stream>>>(
      eq, gcnt, E, NB, qnodes, kvnodes, W, pb, aw, Kp16, sq, sk, Nq, Nk,
      projBlocks);

  // --- scan + binning ---
  bucket_scan<<<1, 1024, 0, stream>>>(gcnt, gbase, gcursor, NB);
  bin_kernel<<<(E + CHUNK - 1) / CHUNK, 1024, 0, stream>>>(eq, ek, gcursor,
                                                           pairs, E, NB);

  // --- fused bucket sort + transposed aggregation ---
  sort_agg_kernel<<<NB, 512, 0, stream>>>(pairs, gcnt, gbase, sq, sk, ab,
                                          Kp16, (float*)d_out, Nq);
}